// Round 7
// baseline (50.747 us; speedup 1.0000x reference)
//
#include <hip/hip_runtime.h>

// Problem constants: B=2, S=4, N=M=4096, fp32 3D points.
constexpr int Sn = 4;
constexpr int Nn = 4096;
constexpr int Mn = 4096;
constexpr int NS2 = 16;               // (dir,slice): z = dir*8 + slice
constexpr int CH  = 16;               // combine-kernel i-range split
constexpr int APT = 8;                // A-points per thread (R3-proven)
constexpr int NBC = 32;               // B-chunks (R3-proven)
constexpr int BCHUNK = Mn / NBC;      // 128

// ws layout: float4 tB[NS2][Mn] (1 MB) | float pmin[NS2][NBC][Nn] (8 MB) | float sums2[NS2][CH]
constexpr size_t TB_FLOAT4S = (size_t)NS2 * Mn;
constexpr size_t PMIN_FLOATS = (size_t)NS2 * NBC * Nn;

// ---- prep: transformed B table. z<8 -> from Y (dir 0 targets), z>=8 -> from X.
__global__ __launch_bounds__(256) void chamfer_prep(
    const float* __restrict__ X, const float* __restrict__ Y,
    float4* __restrict__ tB)
{
    const int idx = blockIdx.x * 256 + threadIdx.x;   // 0..65535
    const int z = idx >> 12;
    const int m = idx & (Mn - 1);
    const float* src = (z < 8) ? (Y + (size_t)z * (Mn * 3))
                               : (X + (size_t)(z - 8) * (Mn * 3));
    const float bx = src[m * 3 + 0];
    const float by = src[m * 3 + 1];
    const float bz = src[m * 3 + 2];
    tB[idx] = make_float4(-2.0f * bx, -2.0f * by, -2.0f * bz,
                          bx * bx + by * by + bz * bz);
}

// ---- partial: no LDS. B comes in as wave-uniform loads (SMEM broadcast to SGPRs).
__global__ __launch_bounds__(256) void chamfer_partial(
    const float* __restrict__ X,
    const float* __restrict__ Y,
    const float4* __restrict__ tB,
    float* __restrict__ pmin)      // [NS2][NBC][Nn]
{
    constexpr int ATILE = APT * 256;

    const int at    = blockIdx.x;
    const int bc    = blockIdx.y;
    const int z     = blockIdx.z;
    const int slice = z & 7;
    const int dir   = z >> 3;
    const int tid   = threadIdx.x;

    const float* A = (dir == 0 ? X : Y) + (size_t)slice * (Nn * 3);
    // Wave-uniform pointer to this block's transformed-B range.
    const float4* __restrict__ tb = tB + (size_t)z * Mn + (size_t)bc * BCHUNK;

    // Register-block APT A-points (strided ownership: n = at*ATILE + j*256 + tid).
    float ax[APT], ay[APT], az[APT], acc[APT];
    #pragma unroll
    for (int j = 0; j < APT; ++j) {
        const int n = at * ATILE + j * 256 + tid;
        ax[j] = A[n * 3 + 0];
        ay[j] = A[n * 3 + 1];
        az[j] = A[n * 3 + 2];
        acc[j] = 3.4e38f;
    }

    // Inner loop: b0/b1 are wave-uniform -> s_load (SMEM pipe, no DS, no LDS).
    // Per pair: 3 v_fma (1 SGPR operand each) + v_min3 per 2 pairs.
    #pragma unroll 4
    for (int m = 0; m < BCHUNK; m += 2) {
        const float4 b0 = tb[m + 0];
        const float4 b1 = tb[m + 1];
        #pragma unroll
        for (int j = 0; j < APT; ++j) {
            float d0 = fmaf(ax[j], b0.x, fmaf(ay[j], b0.y, fmaf(az[j], b0.z, b0.w)));
            float d1 = fmaf(ax[j], b1.x, fmaf(ay[j], b1.y, fmaf(az[j], b1.z, b1.w)));
            acc[j] = fminf(fminf(acc[j], d0), d1);   // -> v_min3_f32
        }
    }

    // Coalesced store of partial mins (+|a|^2 recomputed; constant across chunks)
    float* dst = pmin + ((size_t)z * NBC + bc) * Nn + at * ATILE;
    #pragma unroll
    for (int j = 0; j < APT; ++j) {
        const float a2 = ax[j] * ax[j] + ay[j] * ay[j] + az[j] * az[j];
        dst[j * 256 + tid] = acc[j] + a2;
    }
}

__global__ __launch_bounds__(256) void chamfer_combine(
    const float* __restrict__ pmin, float* __restrict__ sums2)  // sums2[NS2][CH]
{
    const int z   = blockIdx.x;       // 0..15
    const int c   = blockIdx.y;       // 0..CH-1
    const int tid = threadIdx.x;
    constexpr int SPAN = Nn / CH;     // 256

    const float* p = pmin + (size_t)z * NBC * Nn;

    float s = 0.0f;
    for (int i = c * SPAN + tid; i < (c + 1) * SPAN; i += 256) {
        float m = p[i];
        #pragma unroll 8
        for (int bc = 1; bc < NBC; ++bc) m = fminf(m, p[(size_t)bc * Nn + i]);
        s += m;
    }

    s += __shfl_down(s, 32);
    s += __shfl_down(s, 16);
    s += __shfl_down(s, 8);
    s += __shfl_down(s, 4);
    s += __shfl_down(s, 2);
    s += __shfl_down(s, 1);

    __shared__ float red[4];
    if ((tid & 63) == 0) red[tid >> 6] = s;
    __syncthreads();
    if (tid == 0) sums2[z * CH + c] = red[0] + red[1] + red[2] + red[3];
}

__global__ __launch_bounds__(64) void chamfer_finalize(
    const float* __restrict__ sums2, float* __restrict__ out)
{
    const int tid = threadIdx.x;
    // total[z] = sum_c sums2[z][c]; z = dir*8 + (b*4 + s)
    __shared__ float tot[NS2];
    if (tid < NS2) {
        float t = 0.0f;
        #pragma unroll
        for (int c = 0; c < CH; ++c) t += sums2[tid * CH + c];
        tot[tid] = t;
    }
    __syncthreads();
    if (tid < 8) {
        const int s = tid >> 1, b = tid & 1;
        const int l = b * Sn + s;
        out[4 + s * 2 + b] = tot[l] * (1.0f / Nn) + tot[8 + l] * (1.0f / Mn);
    } else if (tid < 12) {
        const int s = tid - 8;
        float c0 = tot[0 * Sn + s] * (1.0f / Nn) + tot[8 + 0 * Sn + s] * (1.0f / Mn);
        float c1 = tot[1 * Sn + s] * (1.0f / Nn) + tot[8 + 1 * Sn + s] * (1.0f / Mn);
        out[s] = 0.5f * (c0 + c1);
    }
}

extern "C" void kernel_launch(void* const* d_in, const int* in_sizes, int n_in,
                              void* d_out, int out_size, void* d_ws, size_t ws_size,
                              hipStream_t stream) {
    const float* X = (const float*)d_in[0];   // output_points [2,4,4096,3]
    const float* Y = (const float*)d_in[1];   // target_points [2,4,4096,3]
    float* out = (float*)d_out;               // 12 floats

    float4* tB   = (float4*)d_ws;                       // 1 MB
    float*  pmin = (float*)d_ws + 4 * TB_FLOAT4S;       // 8 MB
    float*  sums2 = pmin + PMIN_FLOATS;                 // 256 floats

    // prep: 65536 transformed B points
    chamfer_prep<<<NS2 * Mn / 256, 256, 0, stream>>>(X, Y, tB);

    // partial: grid (2, 32, 16) = 1024 blocks (4/CU), APT=8, BCHUNK=128 (R3 geometry)
    dim3 grid(Nn / (APT * 256), NBC, NS2);
    chamfer_partial<<<grid, 256, 0, stream>>>(X, Y, tB, pmin);

    chamfer_combine<<<dim3(NS2, CH), 256, 0, stream>>>(pmin, sums2);
    chamfer_finalize<<<1, 64, 0, stream>>>(sums2, out);
}

// Round 8
// 38.543 us; speedup vs baseline: 1.3166x; 1.3166x over previous
//
#include <hip/hip_runtime.h>

// Problem constants: B=2, S=4, N=M=4096, fp32 3D points.
constexpr int Sn = 4;
constexpr int Nn = 4096;
constexpr int Mn = 4096;
constexpr int NS2 = 16;               // (dir,slice): z = dir*8 + slice
constexpr int CH  = 16;               // combine-kernel i-range split
constexpr int APT = 8;                // A-points per thread (R3-proven)
constexpr int NBC = 32;               // B-chunks (R3-proven)
constexpr int BCHUNK = Mn / NBC;      // 128

// ws layout: float pmin[NS2][NBC][Nn] (8 MB) | float sums2[NS2][CH]
constexpr size_t PMIN_FLOATS = (size_t)NS2 * NBC * Nn;

__global__ __launch_bounds__(256) void chamfer_partial(
    const float* __restrict__ X,   // output_points [8][4096][3]
    const float* __restrict__ Y,   // target_points [8][4096][3]
    float* __restrict__ pmin)      // [NS2][NBC][Nn]
{
    constexpr int ATILE = APT * 256;

    __shared__ float4 ldsB[BCHUNK];

    const int at    = blockIdx.x;
    const int bc    = blockIdx.y;
    const int z     = blockIdx.z;
    const int slice = z & 7;
    const int dir   = z >> 3;
    const int tid   = threadIdx.x;

    const float* A  = (dir == 0 ? X : Y) + (size_t)slice * (Nn * 3);
    const float* Bp = (dir == 0 ? Y : X) + (size_t)slice * (Mn * 3) + bc * (BCHUNK * 3);

    // Register-block APT A-points (strided ownership: n = at*ATILE + j*256 + tid).
    float ax[APT], ay[APT], az[APT], acc[APT];
    #pragma unroll
    for (int j = 0; j < APT; ++j) {
        const int n = at * ATILE + j * 256 + tid;
        ax[j] = A[n * 3 + 0];
        ay[j] = A[n * 3 + 1];
        az[j] = A[n * 3 + 2];
        acc[j] = 3.4e38f;
    }

    // Stage B chunk pre-transformed: (-2bx, -2by, -2bz, |b|^2)
    for (int p = tid; p < BCHUNK; p += 256) {
        float bx = Bp[p * 3 + 0], by = Bp[p * 3 + 1], bz = Bp[p * 3 + 2];
        ldsB[p] = make_float4(-2.0f * bx, -2.0f * by, -2.0f * bz,
                              bx * bx + by * by + bz * bz);
    }
    __syncthreads();

    // Wave-staggered circular scan: wave w starts at m = w*32. The 4 waves'
    // DS-read bursts then interleave with other waves' VALU phases instead of
    // colliding on the per-CU DS pipe (burst-oscillation fix).
    const int woff = (tid >> 6) * (BCHUNK / 4);   // 0,32,64,96 (wave-uniform)

    #define CHAMFER_BODY(mv)                                                        \
        {                                                                           \
            const float4 b0 = ldsB[(mv) + 0];                                       \
            const float4 b1 = ldsB[(mv) + 1];                                       \
            _Pragma("unroll")                                                       \
            for (int j = 0; j < APT; ++j) {                                         \
                float d0 = fmaf(ax[j], b0.x, fmaf(ay[j], b0.y, fmaf(az[j], b0.z, b0.w))); \
                float d1 = fmaf(ax[j], b1.x, fmaf(ay[j], b1.y, fmaf(az[j], b1.z, b1.w))); \
                acc[j] = fminf(fminf(acc[j], d0), d1);                              \
            }                                                                       \
        }

    #pragma unroll 4
    for (int m = woff; m < BCHUNK; m += 2) CHAMFER_BODY(m)
    #pragma unroll 4
    for (int m = 0; m < woff; m += 2) CHAMFER_BODY(m)

    #undef CHAMFER_BODY

    // Coalesced store of partial mins (+|a|^2 recomputed; constant across chunks)
    float* dst = pmin + ((size_t)z * NBC + bc) * Nn + at * ATILE;
    #pragma unroll
    for (int j = 0; j < APT; ++j) {
        const float a2 = ax[j] * ax[j] + ay[j] * ay[j] + az[j] * az[j];
        dst[j * 256 + tid] = acc[j] + a2;
    }
}

__global__ __launch_bounds__(256) void chamfer_combine(
    const float* __restrict__ pmin, float* __restrict__ sums2)  // sums2[NS2][CH]
{
    const int z   = blockIdx.x;       // 0..15
    const int c   = blockIdx.y;       // 0..CH-1
    const int tid = threadIdx.x;
    constexpr int SPAN = Nn / CH;     // 256

    const float* p = pmin + (size_t)z * NBC * Nn;

    float s = 0.0f;
    for (int i = c * SPAN + tid; i < (c + 1) * SPAN; i += 256) {
        float m = p[i];
        #pragma unroll 8
        for (int bc = 1; bc < NBC; ++bc) m = fminf(m, p[(size_t)bc * Nn + i]);
        s += m;
    }

    s += __shfl_down(s, 32);
    s += __shfl_down(s, 16);
    s += __shfl_down(s, 8);
    s += __shfl_down(s, 4);
    s += __shfl_down(s, 2);
    s += __shfl_down(s, 1);

    __shared__ float red[4];
    if ((tid & 63) == 0) red[tid >> 6] = s;
    __syncthreads();
    if (tid == 0) sums2[z * CH + c] = red[0] + red[1] + red[2] + red[3];
}

__global__ __launch_bounds__(64) void chamfer_finalize(
    const float* __restrict__ sums2, float* __restrict__ out)
{
    const int tid = threadIdx.x;
    // total[z] = sum_c sums2[z][c]; z = dir*8 + (b*4 + s)
    __shared__ float tot[NS2];
    if (tid < NS2) {
        float t = 0.0f;
        #pragma unroll
        for (int c = 0; c < CH; ++c) t += sums2[tid * CH + c];
        tot[tid] = t;
    }
    __syncthreads();
    if (tid < 8) {
        const int s = tid >> 1, b = tid & 1;
        const int l = b * Sn + s;
        out[4 + s * 2 + b] = tot[l] * (1.0f / Nn) + tot[8 + l] * (1.0f / Mn);
    } else if (tid < 12) {
        const int s = tid - 8;
        float c0 = tot[0 * Sn + s] * (1.0f / Nn) + tot[8 + 0 * Sn + s] * (1.0f / Mn);
        float c1 = tot[1 * Sn + s] * (1.0f / Nn) + tot[8 + 1 * Sn + s] * (1.0f / Mn);
        out[s] = 0.5f * (c0 + c1);
    }
}

extern "C" void kernel_launch(void* const* d_in, const int* in_sizes, int n_in,
                              void* d_out, int out_size, void* d_ws, size_t ws_size,
                              hipStream_t stream) {
    const float* X = (const float*)d_in[0];   // output_points [2,4,4096,3]
    const float* Y = (const float*)d_in[1];   // target_points [2,4,4096,3]
    float* out  = (float*)d_out;              // 12 floats
    float* pmin = (float*)d_ws;               // 8 MB
    float* sums2 = pmin + PMIN_FLOATS;        // 256 floats

    dim3 grid(Nn / (APT * 256), NBC, NS2);    // (2, 32, 16) = 1024 blocks (4/CU)
    chamfer_partial<<<grid, 256, 0, stream>>>(X, Y, pmin);
    chamfer_combine<<<dim3(NS2, CH), 256, 0, stream>>>(pmin, sums2);
    chamfer_finalize<<<1, 64, 0, stream>>>(sums2, out);
}